// Round 8
// baseline (188.734 us; speedup 1.0000x reference)
//
#include <hip/hip_runtime.h>
#include <math.h>

#define BB 4
#define LL 512
#define DD 256
#define HH 8
#define DHH 32
#define NB 12  // BUCKETS + 1 (row 11 is the zero padding row)

// K1: QKV projections. Round-7 retile: 192 blocks (3 mats x 64), 32 rows/block,
// thread = 8 rows x 4 cols (acc[8][4]). W L2 traffic: 1MB/block for 32 rows
// = 192MB total (was 768MB at 8 rows/block) -> ~4x less L2 time.
// xs reads are wave-uniform (broadcast); W reads coalesced 1KB/instr.
__global__ __launch_bounds__(256, 4) void qkv_kernel(const float* __restrict__ x,
    const float* __restrict__ Wq, const float* __restrict__ bq,
    const float* __restrict__ Wk, const float* __restrict__ bk,
    const float* __restrict__ Wv, const float* __restrict__ bv,
    const float* __restrict__ uvec, const float* __restrict__ vvec,
    float* __restrict__ Qu, float* __restrict__ Qv,
    float* __restrict__ KT, float* __restrict__ V) {
    __shared__ float xs[32][DD];        // 32 KB
    const int mat = blockIdx.x >> 6;    // 0=Q, 1=K, 2=V
    const int r0 = (blockIdx.x & 63) * 32;
    const int t = threadIdx.x;
    const int cg = t & 63, rg = t >> 6;
    const int c0 = cg * 4;
    {
        const float4* xg = (const float4*)(x + r0 * DD);
        float4* xsv = (float4*)&xs[0][0];
#pragma unroll
        for (int j = 0; j < 8; ++j) xsv[t + 256 * j] = xg[t + 256 * j];
    }
    __syncthreads();
    const float* W    = (mat == 0) ? Wq : (mat == 1) ? Wk : Wv;
    const float* bias = (mat == 0) ? bq : (mat == 1) ? bk : bv;
    float acc[8][4];
#pragma unroll
    for (int r = 0; r < 8; ++r)
#pragma unroll
        for (int c = 0; c < 4; ++c) acc[r][c] = bias[c0 + c];
    for (int i0 = 0; i0 < DD; i0 += 4) {
        float4 wv4[4];
#pragma unroll
        for (int j = 0; j < 4; ++j) wv4[j] = *(const float4*)&W[(i0 + j) * DD + c0];
        float4 xv[8];
#pragma unroll
        for (int r = 0; r < 8; ++r) xv[r] = *(const float4*)&xs[rg * 8 + r][i0];  // wave-uniform
        const float* wf = (const float*)wv4;
#pragma unroll
        for (int r = 0; r < 8; ++r) {
            const float* xf = (const float*)&xv[r];
#pragma unroll
            for (int j = 0; j < 4; ++j)
#pragma unroll
                for (int c = 0; c < 4; ++c)
                    acc[r][c] = fmaf(xf[j], wf[j * 4 + c], acc[r][c]);
        }
    }
    if (mat == 0) {
        const float s = 0.17677669529663687f;  // 1/sqrt(DH)
        const float4 u4 = *(const float4*)&uvec[c0];
        const float4 v4 = *(const float4*)&vvec[c0];
#pragma unroll
        for (int r = 0; r < 8; ++r) {
            const int row = r0 + rg * 8 + r;
            float4 q = make_float4(acc[r][0] * s, acc[r][1] * s, acc[r][2] * s, acc[r][3] * s);
            *(float4*)&Qu[row * DD + c0] = make_float4(q.x + u4.x, q.y + u4.y, q.z + u4.z, q.w + u4.w);
            *(float4*)&Qv[row * DD + c0] = make_float4(q.x + v4.x, q.y + v4.y, q.z + v4.z, q.w + v4.w);
        }
    } else if (mat == 1) {
        const int b = r0 >> 9;                  // 32-row blocks never cross a b boundary
        const int kb = (r0 & 511) + rg * 8;
#pragma unroll
        for (int c = 0; c < 4; ++c) {
            const int col = c0 + c;
            const int h = col >> 5, dd = col & 31;
            float* p = KT + ((long)((b * HH + h) * DHH + dd)) * LL + kb;
            *(float4*)&p[0] = make_float4(acc[0][c], acc[1][c], acc[2][c], acc[3][c]);
            *(float4*)&p[4] = make_float4(acc[4][c], acc[5][c], acc[6][c], acc[7][c]);
        }
    } else {
#pragma unroll
        for (int r = 0; r < 8; ++r)
            *(float4*)&V[(r0 + rg * 8 + r) * DD + c0] =
                make_float4(acc[r][0], acc[r][1], acc[r][2], acc[r][3]);
    }
}

// K2: fused rel-P + scores + softmax + attn write + ctx.
// Round-7: phase A re-tiled for arithmetic intensity. r6 proved the 44us is
// pipe TRAFFIC, not which pipe: wave covered 2 rows x all 512 k -> 5.3 FMA
// per b128. Now wave = (rw 0..3, sw 0..1): 4 rows x one 256-k half -> 8 FMA
// per b128, K traffic halves (each K dword read by 4 waves not 8; 256KB/blk),
// Q re-reads per FLOP halve. K back from GLOBAL (L2; r6 showed LDS==L2 here),
// no Ks staging, LDS stays 35.8KB -> 4 blocks/CU full residency.
// Softmax: per-wave shfl sum over own half, combine halves via psum[2][16]
// (+1 barrier). NOTHING new lives across the d8 loop (r1/r3 spill lesson:
// the loop-internal window is kv[8]+Q frags, same shape as proven r5 body).
// ss swizzle unchanged: ss[q*512 + ch*128 + ((oct^(q>>2))<<3 | h4)].
// Phase B verbatim r5: thread=(qt,dt,kg), 4qx4d reg tile, sv b128 from ss,
// V[k][4d] float4 direct from global; kg-partials reduced via ss alias.
__global__ __launch_bounds__(512, 4) void scores_ctx_kernel(const float* __restrict__ Qu,
    const float* __restrict__ Qv, const float* __restrict__ KT,
    const float* __restrict__ rel_table, const int* __restrict__ mask,
    const int* __restrict__ dist, const float* __restrict__ V,
    float* __restrict__ attn, float* __restrict__ ctx) {
    __shared__ float Qs[16][DHH];
    __shared__ float Ps[16][NB];
    __shared__ float psum[2][16];       // softmax half-sums
    __shared__ float ss[16 * 512];      // swizzled S tile (32KB); preamble aliases Qv8/rels; epilogue aliases partials
    const int blk = blockIdx.x;         // ((b*32 + qt16)*8 + h)
    const int h = blk & 7;
    const int rest = blk >> 3;
    const int qt16 = rest & 31;
    const int b = rest >> 5;
    const int q0 = qt16 * 16;
    const int t = threadIdx.x;
    const int w = t >> 6, l = t & 63;

    float* Qv8  = ss;                   // [16][32]  (dead after Ps compute)
    float* rels = ss + 512;             // [12][33]  (dead after Ps compute)

    {
        const int r = t >> 5, c = t & 31;
        Qs[r][c]          = Qu[(b * LL + q0 + r) * DD + h * DHH + c];
        Qv8[r * DHH + c]  = Qv[(b * LL + q0 + r) * DD + h * DHH + c];
    }
    if (t < NB * DHH) {
        rels[(t >> 5) * 33 + (t & 31)] = rel_table[(t >> 5) * DD + h * DHH + (t & 31)];
    }
    __syncthreads();
    if (t < 16 * NB) {                  // Ps[r][bk] = dot32(Qv8[r], rels[bk])
        const int bk = t >> 4, r = t & 15;
        float a = 0.f;
#pragma unroll
        for (int d = 0; d < DHH; ++d) a = fmaf(Qv8[r * DHH + d], rels[bk * 33 + d], a);
        Ps[r][bk] = a;
    }
    __syncthreads();                    // Qv8/rels dead; ss writable

    // ---- Phase A: wave (rw,sw) does q rows 4rw..4rw+3 over k-half sw ----
    const int rw = w & 3, sw = w >> 2;
    const int r0 = 4 * rw;
    const int k0 = 4 * l + 256 * sw;
    const long kbase = (long)(b * HH + h) * DHH * LL;
    float s0[4], s1[4], s2[4], s3[4];
    {
        const int4 dx0 = *(const int4*)&dist[(b * LL + q0 + r0) * LL + k0];
        const int4 dx1 = *(const int4*)&dist[(b * LL + q0 + r0 + 1) * LL + k0];
        const int4 dx2 = *(const int4*)&dist[(b * LL + q0 + r0 + 2) * LL + k0];
        const int4 dx3 = *(const int4*)&dist[(b * LL + q0 + r0 + 3) * LL + k0];
        s0[0] = Ps[r0][dx0.x];     s0[1] = Ps[r0][dx0.y];     s0[2] = Ps[r0][dx0.z];     s0[3] = Ps[r0][dx0.w];
        s1[0] = Ps[r0 + 1][dx1.x]; s1[1] = Ps[r0 + 1][dx1.y]; s1[2] = Ps[r0 + 1][dx1.z]; s1[3] = Ps[r0 + 1][dx1.w];
        s2[0] = Ps[r0 + 2][dx2.x]; s2[1] = Ps[r0 + 2][dx2.y]; s2[2] = Ps[r0 + 2][dx2.z]; s2[3] = Ps[r0 + 2][dx2.w];
        s3[0] = Ps[r0 + 3][dx3.x]; s3[1] = Ps[r0 + 3][dx3.y]; s3[2] = Ps[r0 + 3][dx3.z]; s3[3] = Ps[r0 + 3][dx3.w];
    }
#pragma unroll
    for (int d8 = 0; d8 < DHH; d8 += 8) {
        float4 kv[8];                        // 8 loads in flight (L2)
#pragma unroll
        for (int j = 0; j < 8; ++j)
            kv[j] = *(const float4*)&KT[kbase + (long)(d8 + j) * LL + k0];
        const float4 q0a = *(const float4*)&Qs[r0][d8];       // wave-uniform
        const float4 q0b = *(const float4*)&Qs[r0][d8 + 4];
        const float4 q1a = *(const float4*)&Qs[r0 + 1][d8];
        const float4 q1b = *(const float4*)&Qs[r0 + 1][d8 + 4];
        const float4 q2a = *(const float4*)&Qs[r0 + 2][d8];
        const float4 q2b = *(const float4*)&Qs[r0 + 2][d8 + 4];
        const float4 q3a = *(const float4*)&Qs[r0 + 3][d8];
        const float4 q3b = *(const float4*)&Qs[r0 + 3][d8 + 4];
        const float* qa0 = (const float*)&q0a; const float* qb0 = (const float*)&q0b;
        const float* qa1 = (const float*)&q1a; const float* qb1 = (const float*)&q1b;
        const float* qa2 = (const float*)&q2a; const float* qb2 = (const float*)&q2b;
        const float* qa3 = (const float*)&q3a; const float* qb3 = (const float*)&q3b;
#pragma unroll
        for (int j = 0; j < 4; ++j) {
            s0[0] = fmaf(qa0[j], kv[j].x, s0[0]); s0[1] = fmaf(qa0[j], kv[j].y, s0[1]);
            s0[2] = fmaf(qa0[j], kv[j].z, s0[2]); s0[3] = fmaf(qa0[j], kv[j].w, s0[3]);
            s1[0] = fmaf(qa1[j], kv[j].x, s1[0]); s1[1] = fmaf(qa1[j], kv[j].y, s1[1]);
            s1[2] = fmaf(qa1[j], kv[j].z, s1[2]); s1[3] = fmaf(qa1[j], kv[j].w, s1[3]);
            s2[0] = fmaf(qa2[j], kv[j].x, s2[0]); s2[1] = fmaf(qa2[j], kv[j].y, s2[1]);
            s2[2] = fmaf(qa2[j], kv[j].z, s2[2]); s2[3] = fmaf(qa2[j], kv[j].w, s2[3]);
            s3[0] = fmaf(qa3[j], kv[j].x, s3[0]); s3[1] = fmaf(qa3[j], kv[j].y, s3[1]);
            s3[2] = fmaf(qa3[j], kv[j].z, s3[2]); s3[3] = fmaf(qa3[j], kv[j].w, s3[3]);
        }
#pragma unroll
        for (int j = 0; j < 4; ++j) {
            s0[0] = fmaf(qb0[j], kv[j + 4].x, s0[0]); s0[1] = fmaf(qb0[j], kv[j + 4].y, s0[1]);
            s0[2] = fmaf(qb0[j], kv[j + 4].z, s0[2]); s0[3] = fmaf(qb0[j], kv[j + 4].w, s0[3]);
            s1[0] = fmaf(qb1[j], kv[j + 4].x, s1[0]); s1[1] = fmaf(qb1[j], kv[j + 4].y, s1[1]);
            s1[2] = fmaf(qb1[j], kv[j + 4].z, s1[2]); s1[3] = fmaf(qb1[j], kv[j + 4].w, s1[3]);
            s2[0] = fmaf(qb2[j], kv[j + 4].x, s2[0]); s2[1] = fmaf(qb2[j], kv[j + 4].y, s2[1]);
            s2[2] = fmaf(qb2[j], kv[j + 4].z, s2[2]); s2[3] = fmaf(qb2[j], kv[j + 4].w, s2[3]);
            s3[0] = fmaf(qb3[j], kv[j + 4].x, s3[0]); s3[1] = fmaf(qb3[j], kv[j + 4].y, s3[1]);
            s3[2] = fmaf(qb3[j], kv[j + 4].z, s3[2]); s3[3] = fmaf(qb3[j], kv[j + 4].w, s3[3]);
        }
    }
    float e0[4], e1[4], e2[4], e3[4];
    {
        const int4 mx0 = *(const int4*)&mask[(b * LL + q0 + r0) * LL + k0];
        const int4 mx1 = *(const int4*)&mask[(b * LL + q0 + r0 + 1) * LL + k0];
        const int4 mx2 = *(const int4*)&mask[(b * LL + q0 + r0 + 2) * LL + k0];
        const int4 mx3 = *(const int4*)&mask[(b * LL + q0 + r0 + 3) * LL + k0];
        e0[0] = mx0.x ? 0.f : __expf(s0[0]); e0[1] = mx0.y ? 0.f : __expf(s0[1]);
        e0[2] = mx0.z ? 0.f : __expf(s0[2]); e0[3] = mx0.w ? 0.f : __expf(s0[3]);
        e1[0] = mx1.x ? 0.f : __expf(s1[0]); e1[1] = mx1.y ? 0.f : __expf(s1[1]);
        e1[2] = mx1.z ? 0.f : __expf(s1[2]); e1[3] = mx1.w ? 0.f : __expf(s1[3]);
        e2[0] = mx2.x ? 0.f : __expf(s2[0]); e2[1] = mx2.y ? 0.f : __expf(s2[1]);
        e2[2] = mx2.z ? 0.f : __expf(s2[2]); e2[3] = mx2.w ? 0.f : __expf(s2[3]);
        e3[0] = mx3.x ? 0.f : __expf(s3[0]); e3[1] = mx3.y ? 0.f : __expf(s3[1]);
        e3[2] = mx3.z ? 0.f : __expf(s3[2]); e3[3] = mx3.w ? 0.f : __expf(s3[3]);
    }
    float sm0 = (e0[0] + e0[1]) + (e0[2] + e0[3]);
    float sm1 = (e1[0] + e1[1]) + (e1[2] + e1[3]);
    float sm2 = (e2[0] + e2[1]) + (e2[2] + e2[3]);
    float sm3 = (e3[0] + e3[1]) + (e3[2] + e3[3]);
    for (int off = 32; off > 0; off >>= 1) {
        sm0 += __shfl_xor(sm0, off);
        sm1 += __shfl_xor(sm1, off);
        sm2 += __shfl_xor(sm2, off);
        sm3 += __shfl_xor(sm3, off);
    }
    if (l == 0) {
        psum[sw][r0]     = sm0;
        psum[sw][r0 + 1] = sm1;
        psum[sw][r0 + 2] = sm2;
        psum[sw][r0 + 3] = sm3;
    }
    __syncthreads();                    // halves combined; also fences ss writable
    const float inv0 = 1.0f / (psum[0][r0]     + psum[1][r0]);
    const float inv1 = 1.0f / (psum[0][r0 + 1] + psum[1][r0 + 1]);
    const float inv2 = 1.0f / (psum[0][r0 + 2] + psum[1][r0 + 2]);
    const float inv3 = 1.0f / (psum[0][r0 + 3] + psum[1][r0 + 3]);
    {
        float* a0 = attn + ((long)(b * HH + h) * LL + q0 + r0) * LL + k0;
        const int ch = k0 >> 7;
        const int oct = (k0 & 127) >> 3;
        const int h4 = k0 & 4;
        const int sbase = ch * 128 + (((oct ^ rw) << 3) | h4);   // (q>>2)==rw for all 4 rows
        const float4 o0 = make_float4(e0[0] * inv0, e0[1] * inv0, e0[2] * inv0, e0[3] * inv0);
        const float4 o1 = make_float4(e1[0] * inv1, e1[1] * inv1, e1[2] * inv1, e1[3] * inv1);
        const float4 o2 = make_float4(e2[0] * inv2, e2[1] * inv2, e2[2] * inv2, e2[3] * inv2);
        const float4 o3 = make_float4(e3[0] * inv3, e3[1] * inv3, e3[2] * inv3, e3[3] * inv3);
        *(float4*)&a0[0]      = o0;
        *(float4*)&a0[LL]     = o1;
        *(float4*)&a0[2 * LL] = o2;
        *(float4*)&a0[3 * LL] = o3;
        *(float4*)&ss[(r0)     * 512 + sbase] = o0;
        *(float4*)&ss[(r0 + 1) * 512 + sbase] = o1;
        *(float4*)&ss[(r0 + 2) * 512 + sbase] = o2;
        *(float4*)&ss[(r0 + 3) * 512 + sbase] = o3;
    }

    // ---- Phase B: ctx via 4q x 4d register tiles; V direct from global (L2) ----
    const int qt = t & 3;               // q-tile (rows 4qt..4qt+3); == q>>2 for its rows
    const int dt = (t >> 2) & 7;        // d-tile (cols 4dt..4dt+3)
    const int kg = t >> 5;              // k-octet within chunk (0..15)
    const float* vbase = V + (long)b * LL * DD + h * DHH + dt * 4;
    float acc[4][4];
#pragma unroll
    for (int i = 0; i < 4; ++i)
#pragma unroll
        for (int jd = 0; jd < 4; ++jd) acc[i][jd] = 0.f;
    __syncthreads();                    // ss fully written
#pragma unroll 1
    for (int c = 0; c < 4; ++c) {
#pragma unroll
        for (int ki = 0; ki < 2; ++ki) {
            float4 sv[4];               // 4 consecutive k of rows qt*4..qt*4+3
#pragma unroll
            for (int i = 0; i < 4; ++i)
                sv[i] = *(const float4*)&ss[(qt * 4 + i) * 512 + c * 128 + (((kg ^ qt) << 3) | (ki << 2))];
#pragma unroll
            for (int j = 0; j < 4; ++j) {
                const int k = c * 128 + (kg << 3) + (ki << 2) + j;
                const float4 vf = *(const float4*)&vbase[k * DD];
                const float w0 = ((const float*)&sv[0])[j];
                const float w1 = ((const float*)&sv[1])[j];
                const float w2 = ((const float*)&sv[2])[j];
                const float w3 = ((const float*)&sv[3])[j];
                acc[0][0] = fmaf(w0, vf.x, acc[0][0]); acc[0][1] = fmaf(w0, vf.y, acc[0][1]);
                acc[0][2] = fmaf(w0, vf.z, acc[0][2]); acc[0][3] = fmaf(w0, vf.w, acc[0][3]);
                acc[1][0] = fmaf(w1, vf.x, acc[1][0]); acc[1][1] = fmaf(w1, vf.y, acc[1][1]);
                acc[1][2] = fmaf(w1, vf.z, acc[1][2]); acc[1][3] = fmaf(w1, vf.w, acc[1][3]);
                acc[2][0] = fmaf(w2, vf.x, acc[2][0]); acc[2][1] = fmaf(w2, vf.y, acc[2][1]);
                acc[2][2] = fmaf(w2, vf.z, acc[2][2]); acc[2][3] = fmaf(w2, vf.w, acc[2][3]);
                acc[3][0] = fmaf(w3, vf.x, acc[3][0]); acc[3][1] = fmaf(w3, vf.y, acc[3][1]);
                acc[3][2] = fmaf(w3, vf.z, acc[3][2]); acc[3][3] = fmaf(w3, vf.w, acc[3][3]);
            }
        }
    }
    // kg-reduction: partials[kg][q][d] reuse ss (exactly 16*512 floats).
    __syncthreads();                    // all phase-B ss reads done
#pragma unroll
    for (int i = 0; i < 4; ++i)
        *(float4*)&ss[kg * 512 + (qt * 4 + i) * 32 + dt * 4] =
            make_float4(acc[i][0], acc[i][1], acc[i][2], acc[i][3]);
    __syncthreads();
    {
        const int qr = t >> 5, dr = t & 31;   // reads: bank = dr -> 2-way (free)
        float r = 0.f;
#pragma unroll
        for (int kg2 = 0; kg2 < 16; ++kg2) r += ss[kg2 * 512 + qr * 32 + dr];
        ctx[(b * LL + q0 + qr) * DD + h * DHH + dr] = r;
    }
}

// K3: output projection. Round-7 retile: 64 blocks x 32 rows, thread = 8 rows
// x 4 cols. W L2 traffic 512MB -> 64MB.
__global__ __launch_bounds__(256, 4) void outproj_kernel(const float* __restrict__ ctx,
    const float* __restrict__ Wo, const float* __restrict__ bo,
    float* __restrict__ out) {
    __shared__ float xs[32][DD];
    const int r0 = blockIdx.x * 32;
    const int t = threadIdx.x;
    const int cg = t & 63, rg = t >> 6;
    const int c0 = cg * 4;
    {
        const float4* xg = (const float4*)(ctx + r0 * DD);
        float4* xsv = (float4*)&xs[0][0];
#pragma unroll
        for (int j = 0; j < 8; ++j) xsv[t + 256 * j] = xg[t + 256 * j];
    }
    __syncthreads();
    float acc[8][4];
    {
        const float4 b4 = *(const float4*)&bo[c0];
#pragma unroll
        for (int r = 0; r < 8; ++r) {
            acc[r][0] = b4.x; acc[r][1] = b4.y; acc[r][2] = b4.z; acc[r][3] = b4.w;
        }
    }
    for (int i0 = 0; i0 < DD; i0 += 4) {
        float4 wv4[4];
#pragma unroll
        for (int j = 0; j < 4; ++j) wv4[j] = *(const float4*)&Wo[(i0 + j) * DD + c0];
        float4 xv[8];
#pragma unroll
        for (int r = 0; r < 8; ++r) xv[r] = *(const float4*)&xs[rg * 8 + r][i0];  // wave-uniform
        const float* wf = (const float*)wv4;
#pragma unroll
        for (int r = 0; r < 8; ++r) {
            const float* xf = (const float*)&xv[r];
#pragma unroll
            for (int j = 0; j < 4; ++j)
#pragma unroll
                for (int c = 0; c < 4; ++c)
                    acc[r][c] = fmaf(xf[j], wf[j * 4 + c], acc[r][c]);
        }
    }
#pragma unroll
    for (int r = 0; r < 8; ++r)
        *(float4*)&out[(r0 + rg * 8 + r) * DD + c0] =
            make_float4(acc[r][0], acc[r][1], acc[r][2], acc[r][3]);
}

extern "C" void kernel_launch(void* const* d_in, const int* in_sizes, int n_in,
                              void* d_out, int out_size, void* d_ws, size_t ws_size,
                              hipStream_t stream) {
    const float* x    = (const float*)d_in[0];
    const int* mk     = (const int*)d_in[1];   // jax bool -> int32
    const int* dist   = (const int*)d_in[2];
    const float* Wq = (const float*)d_in[3];
    const float* bq = (const float*)d_in[4];
    const float* Wk = (const float*)d_in[5];
    const float* bk = (const float*)d_in[6];
    const float* Wv = (const float*)d_in[7];
    const float* bv = (const float*)d_in[8];
    const float* Wo = (const float*)d_in[9];
    const float* bo = (const float*)d_in[10];
    const float* rel_table = (const float*)d_in[11];
    const float* uvec = (const float*)d_in[12];
    const float* vvec = (const float*)d_in[13];

    float* out  = (float*)d_out;                 // (B,L,D)
    float* attn = out + BB * LL * DD;            // (B,H,L,L)

    float* Qu = (float*)d_ws;                    // q/sqrt(dh) + u
    float* Qv = Qu + BB * LL * DD;               // q/sqrt(dh) + v
    float* KT = Qv + BB * LL * DD;               // [B][H][DH][L]
    float* V  = KT + BB * LL * DD;               // [B][L][D]
    float* C  = V + BB * LL * DD;                // ctx (B,L,D); 10.5 MB ws total

    qkv_kernel<<<3 * 64, 256, 0, stream>>>(x, Wq, bq, Wk, bk, Wv, bv, uvec, vvec,
                                           Qu, Qv, KT, V);
    scores_ctx_kernel<<<BB * (LL / 16) * HH, 512, 0, stream>>>(Qu, Qv, KT, rel_table,
                                                               mk, dist, V, attn, C);
    outproj_kernel<<<BB * LL / 32, 256, 0, stream>>>(C, Wo, bo, out);
}

// Round 9
// 168.213 us; speedup vs baseline: 1.1220x; 1.1220x over previous
//
#include <hip/hip_runtime.h>
#include <math.h>

#define BB 4
#define LL 512
#define DD 256
#define HH 8
#define DHH 32
#define NB 12  // BUCKETS + 1 (row 11 is the zero padding row)

// K1: QKV projections (8-row tiles, 768 blocks = 3 blocks/CU — r8 proved
// 192 blocks starves the grid: <1 block/CU, no latency hiding, +~20us).
// Thread = 2 rows x 4 cols. W-loads widened to 8 float4 in flight (r9).
// mat0 writes Qu=q/sqrt(dh)+u, Qv=q/sqrt(dh)+v; mat1 KT[b][h][d][k]; mat2 V.
__global__ __launch_bounds__(256) void qkv_kernel(const float* __restrict__ x,
    const float* __restrict__ Wq, const float* __restrict__ bq,
    const float* __restrict__ Wk, const float* __restrict__ bk,
    const float* __restrict__ Wv, const float* __restrict__ bv,
    const float* __restrict__ uvec, const float* __restrict__ vvec,
    float* __restrict__ Qu, float* __restrict__ Qv,
    float* __restrict__ KT, float* __restrict__ V) {
    __shared__ float xs[8][DD];
    const int mat = blockIdx.x >> 8;          // 0=Q, 1=K, 2=V
    const int r0 = (blockIdx.x & 255) * 8;
    const int t = threadIdx.x;
    const int cg = t & 63, rg = t >> 6;
    const int c0 = cg * 4;
    {
        const float4* xg = (const float4*)(x + r0 * DD);
        float4* xsv = (float4*)&xs[0][0];
        xsv[t] = xg[t];
        xsv[t + 256] = xg[t + 256];
    }
    __syncthreads();
    const float* W    = (mat == 0) ? Wq : (mat == 1) ? Wk : Wv;
    const float* bias = (mat == 0) ? bq : (mat == 1) ? bk : bv;
    float acc[2][4];
#pragma unroll
    for (int r = 0; r < 2; ++r)
#pragma unroll
        for (int c = 0; c < 4; ++c) acc[r][c] = bias[c0 + c];
    for (int i0 = 0; i0 < DD; i0 += 8) {
        float4 wv4[8];                        // 8 W loads in flight (r9 MLP widen)
#pragma unroll
        for (int j = 0; j < 8; ++j) wv4[j] = *(const float4*)&W[(i0 + j) * DD + c0];
        float4 xv4[2][2];
#pragma unroll
        for (int r = 0; r < 2; ++r) {
            xv4[r][0] = *(const float4*)&xs[rg * 2 + r][i0];
            xv4[r][1] = *(const float4*)&xs[rg * 2 + r][i0 + 4];
        }
#pragma unroll
        for (int r = 0; r < 2; ++r) {
            const float* xf = (const float*)&xv4[r][0];
#pragma unroll
            for (int j = 0; j < 8; ++j) {
                acc[r][0] = fmaf(xf[j], wv4[j].x, acc[r][0]);
                acc[r][1] = fmaf(xf[j], wv4[j].y, acc[r][1]);
                acc[r][2] = fmaf(xf[j], wv4[j].z, acc[r][2]);
                acc[r][3] = fmaf(xf[j], wv4[j].w, acc[r][3]);
            }
        }
    }
    if (mat == 0) {
        const float s = 0.17677669529663687f;  // 1/sqrt(DH)
        const float4 u4 = *(const float4*)&uvec[c0];
        const float4 v4 = *(const float4*)&vvec[c0];
#pragma unroll
        for (int r = 0; r < 2; ++r) {
            const int row = r0 + rg * 2 + r;
            float4 q = make_float4(acc[r][0] * s, acc[r][1] * s, acc[r][2] * s, acc[r][3] * s);
            *(float4*)&Qu[row * DD + c0] = make_float4(q.x + u4.x, q.y + u4.y, q.z + u4.z, q.w + u4.w);
            *(float4*)&Qv[row * DD + c0] = make_float4(q.x + v4.x, q.y + v4.y, q.z + v4.z, q.w + v4.w);
        }
    } else if (mat == 1) {
        const int b = r0 >> 9;
        const int kb = (r0 & 511) + rg * 2;
#pragma unroll
        for (int c = 0; c < 4; ++c) {
            const int col = c0 + c;
            const int h = col >> 5, dd = col & 31;
            float* p = KT + ((long)((b * HH + h) * DHH + dd)) * LL + kb;
            p[0] = acc[0][c];
            p[1] = acc[1][c];
        }
    } else {
#pragma unroll
        for (int r = 0; r < 2; ++r)
            *(float4*)&V[(r0 + rg * 2 + r) * DD + c0] =
                make_float4(acc[r][0], acc[r][1], acc[r][2], acc[r][3]);
    }
}

// K2: fused rel-P + scores + softmax + attn write + ctx. (r8 form, verified)
// Phase A: wave (rw,sw) = 4 q-rows x one 256-k half -> 8 FMA per b128,
// K L2 traffic 256KB/block. Softmax halves combined via psum[2][16].
// NOTHING new lives across the d8 loop (r1/r3 spill lesson).
// ss swizzle: ss[q*512 + ch*128 + ((oct^(q>>2))<<3 | h4)].
// Phase B: thread=(qt,dt,kg), 4qx4d reg tile, sv b128 from ss,
// V[k][4d] float4 direct from global (L2); kg-partials reduced via ss alias.
// LDS 35.8KB -> 4 blocks/CU full residency (1024 blocks all resident).
__global__ __launch_bounds__(512, 4) void scores_ctx_kernel(const float* __restrict__ Qu,
    const float* __restrict__ Qv, const float* __restrict__ KT,
    const float* __restrict__ rel_table, const int* __restrict__ mask,
    const int* __restrict__ dist, const float* __restrict__ V,
    float* __restrict__ attn, float* __restrict__ ctx) {
    __shared__ float Qs[16][DHH];
    __shared__ float Ps[16][NB];
    __shared__ float psum[2][16];       // softmax half-sums
    __shared__ float ss[16 * 512];      // swizzled S tile (32KB); preamble aliases Qv8/rels; epilogue aliases partials
    const int blk = blockIdx.x;         // ((b*32 + qt16)*8 + h)
    const int h = blk & 7;
    const int rest = blk >> 3;
    const int qt16 = rest & 31;
    const int b = rest >> 5;
    const int q0 = qt16 * 16;
    const int t = threadIdx.x;
    const int w = t >> 6, l = t & 63;

    float* Qv8  = ss;                   // [16][32]  (dead after Ps compute)
    float* rels = ss + 512;             // [12][33]  (dead after Ps compute)

    {
        const int r = t >> 5, c = t & 31;
        Qs[r][c]          = Qu[(b * LL + q0 + r) * DD + h * DHH + c];
        Qv8[r * DHH + c]  = Qv[(b * LL + q0 + r) * DD + h * DHH + c];
    }
    if (t < NB * DHH) {
        rels[(t >> 5) * 33 + (t & 31)] = rel_table[(t >> 5) * DD + h * DHH + (t & 31)];
    }
    __syncthreads();
    if (t < 16 * NB) {                  // Ps[r][bk] = dot32(Qv8[r], rels[bk])
        const int bk = t >> 4, r = t & 15;
        float a = 0.f;
#pragma unroll
        for (int d = 0; d < DHH; ++d) a = fmaf(Qv8[r * DHH + d], rels[bk * 33 + d], a);
        Ps[r][bk] = a;
    }
    __syncthreads();                    // Qv8/rels dead; ss writable

    // ---- Phase A: wave (rw,sw) does q rows 4rw..4rw+3 over k-half sw ----
    const int rw = w & 3, sw = w >> 2;
    const int r0 = 4 * rw;
    const int k0 = 4 * l + 256 * sw;
    const long kbase = (long)(b * HH + h) * DHH * LL;
    float s0[4], s1[4], s2[4], s3[4];
    {
        const int4 dx0 = *(const int4*)&dist[(b * LL + q0 + r0) * LL + k0];
        const int4 dx1 = *(const int4*)&dist[(b * LL + q0 + r0 + 1) * LL + k0];
        const int4 dx2 = *(const int4*)&dist[(b * LL + q0 + r0 + 2) * LL + k0];
        const int4 dx3 = *(const int4*)&dist[(b * LL + q0 + r0 + 3) * LL + k0];
        s0[0] = Ps[r0][dx0.x];     s0[1] = Ps[r0][dx0.y];     s0[2] = Ps[r0][dx0.z];     s0[3] = Ps[r0][dx0.w];
        s1[0] = Ps[r0 + 1][dx1.x]; s1[1] = Ps[r0 + 1][dx1.y]; s1[2] = Ps[r0 + 1][dx1.z]; s1[3] = Ps[r0 + 1][dx1.w];
        s2[0] = Ps[r0 + 2][dx2.x]; s2[1] = Ps[r0 + 2][dx2.y]; s2[2] = Ps[r0 + 2][dx2.z]; s2[3] = Ps[r0 + 2][dx2.w];
        s3[0] = Ps[r0 + 3][dx3.x]; s3[1] = Ps[r0 + 3][dx3.y]; s3[2] = Ps[r0 + 3][dx3.z]; s3[3] = Ps[r0 + 3][dx3.w];
    }
#pragma unroll
    for (int d8 = 0; d8 < DHH; d8 += 8) {
        float4 kv[8];                        // 8 loads in flight (L2)
#pragma unroll
        for (int j = 0; j < 8; ++j)
            kv[j] = *(const float4*)&KT[kbase + (long)(d8 + j) * LL + k0];
        const float4 q0a = *(const float4*)&Qs[r0][d8];       // wave-uniform
        const float4 q0b = *(const float4*)&Qs[r0][d8 + 4];
        const float4 q1a = *(const float4*)&Qs[r0 + 1][d8];
        const float4 q1b = *(const float4*)&Qs[r0 + 1][d8 + 4];
        const float4 q2a = *(const float4*)&Qs[r0 + 2][d8];
        const float4 q2b = *(const float4*)&Qs[r0 + 2][d8 + 4];
        const float4 q3a = *(const float4*)&Qs[r0 + 3][d8];
        const float4 q3b = *(const float4*)&Qs[r0 + 3][d8 + 4];
        const float* qa0 = (const float*)&q0a; const float* qb0 = (const float*)&q0b;
        const float* qa1 = (const float*)&q1a; const float* qb1 = (const float*)&q1b;
        const float* qa2 = (const float*)&q2a; const float* qb2 = (const float*)&q2b;
        const float* qa3 = (const float*)&q3a; const float* qb3 = (const float*)&q3b;
#pragma unroll
        for (int j = 0; j < 4; ++j) {
            s0[0] = fmaf(qa0[j], kv[j].x, s0[0]); s0[1] = fmaf(qa0[j], kv[j].y, s0[1]);
            s0[2] = fmaf(qa0[j], kv[j].z, s0[2]); s0[3] = fmaf(qa0[j], kv[j].w, s0[3]);
            s1[0] = fmaf(qa1[j], kv[j].x, s1[0]); s1[1] = fmaf(qa1[j], kv[j].y, s1[1]);
            s1[2] = fmaf(qa1[j], kv[j].z, s1[2]); s1[3] = fmaf(qa1[j], kv[j].w, s1[3]);
            s2[0] = fmaf(qa2[j], kv[j].x, s2[0]); s2[1] = fmaf(qa2[j], kv[j].y, s2[1]);
            s2[2] = fmaf(qa2[j], kv[j].z, s2[2]); s2[3] = fmaf(qa2[j], kv[j].w, s2[3]);
            s3[0] = fmaf(qa3[j], kv[j].x, s3[0]); s3[1] = fmaf(qa3[j], kv[j].y, s3[1]);
            s3[2] = fmaf(qa3[j], kv[j].z, s3[2]); s3[3] = fmaf(qa3[j], kv[j].w, s3[3]);
        }
#pragma unroll
        for (int j = 0; j < 4; ++j) {
            s0[0] = fmaf(qb0[j], kv[j + 4].x, s0[0]); s0[1] = fmaf(qb0[j], kv[j + 4].y, s0[1]);
            s0[2] = fmaf(qb0[j], kv[j + 4].z, s0[2]); s0[3] = fmaf(qb0[j], kv[j + 4].w, s0[3]);
            s1[0] = fmaf(qb1[j], kv[j + 4].x, s1[0]); s1[1] = fmaf(qb1[j], kv[j + 4].y, s1[1]);
            s1[2] = fmaf(qb1[j], kv[j + 4].z, s1[2]); s1[3] = fmaf(qb1[j], kv[j + 4].w, s1[3]);
            s2[0] = fmaf(qb2[j], kv[j + 4].x, s2[0]); s2[1] = fmaf(qb2[j], kv[j + 4].y, s2[1]);
            s2[2] = fmaf(qb2[j], kv[j + 4].z, s2[2]); s2[3] = fmaf(qb2[j], kv[j + 4].w, s2[3]);
            s3[0] = fmaf(qb3[j], kv[j + 4].x, s3[0]); s3[1] = fmaf(qb3[j], kv[j + 4].y, s3[1]);
            s3[2] = fmaf(qb3[j], kv[j + 4].z, s3[2]); s3[3] = fmaf(qb3[j], kv[j + 4].w, s3[3]);
        }
    }
    float e0[4], e1[4], e2[4], e3[4];
    {
        const int4 mx0 = *(const int4*)&mask[(b * LL + q0 + r0) * LL + k0];
        const int4 mx1 = *(const int4*)&mask[(b * LL + q0 + r0 + 1) * LL + k0];
        const int4 mx2 = *(const int4*)&mask[(b * LL + q0 + r0 + 2) * LL + k0];
        const int4 mx3 = *(const int4*)&mask[(b * LL + q0 + r0 + 3) * LL + k0];
        e0[0] = mx0.x ? 0.f : __expf(s0[0]); e0[1] = mx0.y ? 0.f : __expf(s0[1]);
        e0[2] = mx0.z ? 0.f : __expf(s0[2]); e0[3] = mx0.w ? 0.f : __expf(s0[3]);
        e1[0] = mx1.x ? 0.f : __expf(s1[0]); e1[1] = mx1.y ? 0.f : __expf(s1[1]);
        e1[2] = mx1.z ? 0.f : __expf(s1[2]); e1[3] = mx1.w ? 0.f : __expf(s1[3]);
        e2[0] = mx2.x ? 0.f : __expf(s2[0]); e2[1] = mx2.y ? 0.f : __expf(s2[1]);
        e2[2] = mx2.z ? 0.f : __expf(s2[2]); e2[3] = mx2.w ? 0.f : __expf(s2[3]);
        e3[0] = mx3.x ? 0.f : __expf(s3[0]); e3[1] = mx3.y ? 0.f : __expf(s3[1]);
        e3[2] = mx3.z ? 0.f : __expf(s3[2]); e3[3] = mx3.w ? 0.f : __expf(s3[3]);
    }
    float sm0 = (e0[0] + e0[1]) + (e0[2] + e0[3]);
    float sm1 = (e1[0] + e1[1]) + (e1[2] + e1[3]);
    float sm2 = (e2[0] + e2[1]) + (e2[2] + e2[3]);
    float sm3 = (e3[0] + e3[1]) + (e3[2] + e3[3]);
    for (int off = 32; off > 0; off >>= 1) {
        sm0 += __shfl_xor(sm0, off);
        sm1 += __shfl_xor(sm1, off);
        sm2 += __shfl_xor(sm2, off);
        sm3 += __shfl_xor(sm3, off);
    }
    if (l == 0) {
        psum[sw][r0]     = sm0;
        psum[sw][r0 + 1] = sm1;
        psum[sw][r0 + 2] = sm2;
        psum[sw][r0 + 3] = sm3;
    }
    __syncthreads();                    // halves combined; also fences ss writable
    const float inv0 = 1.0f / (psum[0][r0]     + psum[1][r0]);
    const float inv1 = 1.0f / (psum[0][r0 + 1] + psum[1][r0 + 1]);
    const float inv2 = 1.0f / (psum[0][r0 + 2] + psum[1][r0 + 2]);
    const float inv3 = 1.0f / (psum[0][r0 + 3] + psum[1][r0 + 3]);
    {
        float* a0 = attn + ((long)(b * HH + h) * LL + q0 + r0) * LL + k0;
        const int ch = k0 >> 7;
        const int oct = (k0 & 127) >> 3;
        const int h4 = k0 & 4;
        const int sbase = ch * 128 + (((oct ^ rw) << 3) | h4);   // (q>>2)==rw for all 4 rows
        const float4 o0 = make_float4(e0[0] * inv0, e0[1] * inv0, e0[2] * inv0, e0[3] * inv0);
        const float4 o1 = make_float4(e1[0] * inv1, e1[1] * inv1, e1[2] * inv1, e1[3] * inv1);
        const float4 o2 = make_float4(e2[0] * inv2, e2[1] * inv2, e2[2] * inv2, e2[3] * inv2);
        const float4 o3 = make_float4(e3[0] * inv3, e3[1] * inv3, e3[2] * inv3, e3[3] * inv3);
        *(float4*)&a0[0]      = o0;
        *(float4*)&a0[LL]     = o1;
        *(float4*)&a0[2 * LL] = o2;
        *(float4*)&a0[3 * LL] = o3;
        *(float4*)&ss[(r0)     * 512 + sbase] = o0;
        *(float4*)&ss[(r0 + 1) * 512 + sbase] = o1;
        *(float4*)&ss[(r0 + 2) * 512 + sbase] = o2;
        *(float4*)&ss[(r0 + 3) * 512 + sbase] = o3;
    }

    // ---- Phase B: ctx via 4q x 4d register tiles; V direct from global (L2) ----
    const int qt = t & 3;               // q-tile (rows 4qt..4qt+3); == q>>2 for its rows
    const int dt = (t >> 2) & 7;        // d-tile (cols 4dt..4dt+3)
    const int kg = t >> 5;              // k-octet within chunk (0..15)
    const float* vbase = V + (long)b * LL * DD + h * DHH + dt * 4;
    float acc[4][4];
#pragma unroll
    for (int i = 0; i < 4; ++i)
#pragma unroll
        for (int jd = 0; jd < 4; ++jd) acc[i][jd] = 0.f;
    __syncthreads();                    // ss fully written
#pragma unroll 1
    for (int c = 0; c < 4; ++c) {
#pragma unroll
        for (int ki = 0; ki < 2; ++ki) {
            float4 sv[4];               // 4 consecutive k of rows qt*4..qt*4+3
#pragma unroll
            for (int i = 0; i < 4; ++i)
                sv[i] = *(const float4*)&ss[(qt * 4 + i) * 512 + c * 128 + (((kg ^ qt) << 3) | (ki << 2))];
#pragma unroll
            for (int j = 0; j < 4; ++j) {
                const int k = c * 128 + (kg << 3) + (ki << 2) + j;
                const float4 vf = *(const float4*)&vbase[k * DD];
                const float w0 = ((const float*)&sv[0])[j];
                const float w1 = ((const float*)&sv[1])[j];
                const float w2 = ((const float*)&sv[2])[j];
                const float w3 = ((const float*)&sv[3])[j];
                acc[0][0] = fmaf(w0, vf.x, acc[0][0]); acc[0][1] = fmaf(w0, vf.y, acc[0][1]);
                acc[0][2] = fmaf(w0, vf.z, acc[0][2]); acc[0][3] = fmaf(w0, vf.w, acc[0][3]);
                acc[1][0] = fmaf(w1, vf.x, acc[1][0]); acc[1][1] = fmaf(w1, vf.y, acc[1][1]);
                acc[1][2] = fmaf(w1, vf.z, acc[1][2]); acc[1][3] = fmaf(w1, vf.w, acc[1][3]);
                acc[2][0] = fmaf(w2, vf.x, acc[2][0]); acc[2][1] = fmaf(w2, vf.y, acc[2][1]);
                acc[2][2] = fmaf(w2, vf.z, acc[2][2]); acc[2][3] = fmaf(w2, vf.w, acc[2][3]);
                acc[3][0] = fmaf(w3, vf.x, acc[3][0]); acc[3][1] = fmaf(w3, vf.y, acc[3][1]);
                acc[3][2] = fmaf(w3, vf.z, acc[3][2]); acc[3][3] = fmaf(w3, vf.w, acc[3][3]);
            }
        }
    }
    // kg-reduction: partials[kg][q][d] reuse ss (exactly 16*512 floats).
    __syncthreads();                    // all phase-B ss reads done
#pragma unroll
    for (int i = 0; i < 4; ++i)
        *(float4*)&ss[kg * 512 + (qt * 4 + i) * 32 + dt * 4] =
            make_float4(acc[i][0], acc[i][1], acc[i][2], acc[i][3]);
    __syncthreads();
    {
        const int qr = t >> 5, dr = t & 31;   // reads: bank = dr -> 2-way (free)
        float r = 0.f;
#pragma unroll
        for (int kg2 = 0; kg2 < 16; ++kg2) r += ss[kg2 * 512 + qr * 32 + dr];
        ctx[(b * LL + q0 + qr) * DD + h * DHH + dr] = r;
    }
}

// K3: output projection. Block = 4 rows (512 blocks = 2/CU); thread = 1 row x
// 4 cols; 8 W loads in flight. (r6 proven form; r8's 64-block retile starved
// the grid.)
__global__ __launch_bounds__(256) void outproj_kernel(const float* __restrict__ ctx,
    const float* __restrict__ Wo, const float* __restrict__ bo,
    float* __restrict__ out) {
    __shared__ float xs[4][DD];
    const int r0 = blockIdx.x * 4;
    const int t = threadIdx.x;
    const int rg = t >> 6;
    const int c0 = (t & 63) * 4;
    ((float4*)&xs[0][0])[t] = ((const float4*)(ctx + r0 * DD))[t];
    __syncthreads();
    float4 acc = *(const float4*)&bo[c0];
    for (int i0 = 0; i0 < DD; i0 += 8) {
        float4 wv[8];
#pragma unroll
        for (int j = 0; j < 8; ++j) wv[j] = *(const float4*)&Wo[(i0 + j) * DD + c0];
        const float4 x0 = *(const float4*)&xs[rg][i0];
        const float4 x1 = *(const float4*)&xs[rg][i0 + 4];
        const float* xf0 = (const float*)&x0;
        const float* xf1 = (const float*)&x1;
#pragma unroll
        for (int j = 0; j < 4; ++j) {
            acc.x = fmaf(xf0[j], wv[j].x, acc.x);
            acc.y = fmaf(xf0[j], wv[j].y, acc.y);
            acc.z = fmaf(xf0[j], wv[j].z, acc.z);
            acc.w = fmaf(xf0[j], wv[j].w, acc.w);
        }
#pragma unroll
        for (int j = 0; j < 4; ++j) {
            acc.x = fmaf(xf1[j], wv[j + 4].x, acc.x);
            acc.y = fmaf(xf1[j], wv[j + 4].y, acc.y);
            acc.z = fmaf(xf1[j], wv[j + 4].z, acc.z);
            acc.w = fmaf(xf1[j], wv[j + 4].w, acc.w);
        }
    }
    *(float4*)&out[(r0 + rg) * DD + c0] = acc;
}

extern "C" void kernel_launch(void* const* d_in, const int* in_sizes, int n_in,
                              void* d_out, int out_size, void* d_ws, size_t ws_size,
                              hipStream_t stream) {
    const float* x    = (const float*)d_in[0];
    const int* mk     = (const int*)d_in[1];   // jax bool -> int32
    const int* dist   = (const int*)d_in[2];
    const float* Wq = (const float*)d_in[3];
    const float* bq = (const float*)d_in[4];
    const float* Wk = (const float*)d_in[5];
    const float* bk = (const float*)d_in[6];
    const float* Wv = (const float*)d_in[7];
    const float* bv = (const float*)d_in[8];
    const float* Wo = (const float*)d_in[9];
    const float* bo = (const float*)d_in[10];
    const float* rel_table = (const float*)d_in[11];
    const float* uvec = (const float*)d_in[12];
    const float* vvec = (const float*)d_in[13];

    float* out  = (float*)d_out;                 // (B,L,D)
    float* attn = out + BB * LL * DD;            // (B,H,L,L)

    float* Qu = (float*)d_ws;                    // q/sqrt(dh) + u
    float* Qv = Qu + BB * LL * DD;               // q/sqrt(dh) + v
    float* KT = Qv + BB * LL * DD;               // [B][H][DH][L]
    float* V  = KT + BB * LL * DD;               // [B][L][D]
    float* C  = V + BB * LL * DD;                // ctx (B,L,D); 10.5 MB ws total

    qkv_kernel<<<3 * 256, 256, 0, stream>>>(x, Wq, bq, Wk, bk, Wv, bv, uvec, vvec,
                                            Qu, Qv, KT, V);
    scores_ctx_kernel<<<BB * (LL / 16) * HH, 512, 0, stream>>>(Qu, Qv, KT, rel_table,
                                                               mk, dist, V, attn, C);
    outproj_kernel<<<BB * LL / 4, 256, 0, stream>>>(C, Wo, bo, out);
}

// Round 10
// 165.807 us; speedup vs baseline: 1.1383x; 1.0145x over previous
//
#include <hip/hip_runtime.h>
#include <math.h>

#define BB 4
#define LL 512
#define DD 256
#define HH 8
#define DHH 32
#define NB 12  // BUCKETS + 1 (row 11 is the zero padding row)

// K1: QKV projections (8-row tiles, 768 blocks = 3 blocks/CU). Exact r5/r6
// proven form (r9's 8-wide W window was neutral-to-negative; reverted).
__global__ __launch_bounds__(256) void qkv_kernel(const float* __restrict__ x,
    const float* __restrict__ Wq, const float* __restrict__ bq,
    const float* __restrict__ Wk, const float* __restrict__ bk,
    const float* __restrict__ Wv, const float* __restrict__ bv,
    const float* __restrict__ uvec, const float* __restrict__ vvec,
    float* __restrict__ Qu, float* __restrict__ Qv,
    float* __restrict__ KT, float* __restrict__ V) {
    __shared__ float xs[8][DD];
    const int mat = blockIdx.x >> 8;          // 0=Q, 1=K, 2=V
    const int r0 = (blockIdx.x & 255) * 8;
    const int t = threadIdx.x;
    const int cg = t & 63, rg = t >> 6;
    const int c0 = cg * 4;
    {
        const float4* xg = (const float4*)(x + r0 * DD);
        float4* xsv = (float4*)&xs[0][0];
        xsv[t] = xg[t];
        xsv[t + 256] = xg[t + 256];
    }
    __syncthreads();
    const float* W    = (mat == 0) ? Wq : (mat == 1) ? Wk : Wv;
    const float* bias = (mat == 0) ? bq : (mat == 1) ? bk : bv;
    float acc[2][4];
#pragma unroll
    for (int r = 0; r < 2; ++r)
#pragma unroll
        for (int c = 0; c < 4; ++c) acc[r][c] = bias[c0 + c];
    for (int i0 = 0; i0 < DD; i0 += 4) {
        float4 wv4[4], xv4[2];
#pragma unroll
        for (int j = 0; j < 4; ++j) wv4[j] = *(const float4*)&W[(i0 + j) * DD + c0];
#pragma unroll
        for (int r = 0; r < 2; ++r) xv4[r] = *(const float4*)&xs[rg * 2 + r][i0];
        const float* wf = (const float*)wv4;
        const float* xf = (const float*)xv4;
#pragma unroll
        for (int r = 0; r < 2; ++r)
#pragma unroll
            for (int j = 0; j < 4; ++j)
#pragma unroll
                for (int c = 0; c < 4; ++c)
                    acc[r][c] = fmaf(xf[r * 4 + j], wf[j * 4 + c], acc[r][c]);
    }
    if (mat == 0) {
        const float s = 0.17677669529663687f;  // 1/sqrt(DH)
        const float4 u4 = *(const float4*)&uvec[c0];
        const float4 v4 = *(const float4*)&vvec[c0];
#pragma unroll
        for (int r = 0; r < 2; ++r) {
            const int row = r0 + rg * 2 + r;
            float4 q = make_float4(acc[r][0] * s, acc[r][1] * s, acc[r][2] * s, acc[r][3] * s);
            *(float4*)&Qu[row * DD + c0] = make_float4(q.x + u4.x, q.y + u4.y, q.z + u4.z, q.w + u4.w);
            *(float4*)&Qv[row * DD + c0] = make_float4(q.x + v4.x, q.y + v4.y, q.z + v4.z, q.w + v4.w);
        }
    } else if (mat == 1) {
        const int b = r0 >> 9;
        const int kb = (r0 & 511) + rg * 2;
#pragma unroll
        for (int c = 0; c < 4; ++c) {
            const int col = c0 + c;
            const int h = col >> 5, dd = col & 31;
            float* p = KT + ((long)((b * HH + h) * DHH + dd)) * LL + kb;
            p[0] = acc[0][c];
            p[1] = acc[1][c];
        }
    } else {
#pragma unroll
        for (int r = 0; r < 2; ++r)
            *(float4*)&V[(r0 + rg * 2 + r) * DD + c0] =
                make_float4(acc[r][0], acc[r][1], acc[r][2], acc[r][3]);
    }
}

// K2: fused rel-P + scores + softmax + attn write + ctx.
// Round-10: 32-row blocks (512 blocks x 512 thr, 2/CU, LDS 69.8KB).
// Theory: all kernels run ~3x above pipe floors; unifying explanation is
// sustained L2->CU delivery ~50-70GB/s for dependent reads => time tracks L2
// request bytes/CU. Phase A: wave (rw 0..3, sw 0..1) = 8 q-rows x one 256-k
// half; one K-half read serves 8 rows -> K requests 256KB/block = 512KB/CU
// (r5: 2MB, r9: 1MB). Spill protection (r1/r3 lessons): d8 loop pinned
// `#pragma unroll 1` (no cross-iter pipelining; live = 32 acc + 32 kv + 8 Q
// ~= 90 < 128), Q frags loaded per-row INSIDE the loop, nothing else lives
// across it. Softmax: per-row shfl over own half + psum[2][32] combine.
// ss swizzle (64KB, 32 rows): row q, chunk c, octet o at
//   ss[q*512 + c*128 + ((o^(q>>2))<<3 | h4)].
// Phase B: thread = (qt 0..7, dt 0..7, kg=wave 0..7); acc[4][4]; per chunk c
// wave kg covers octets {kg, kg+8}; sv b128 (2 distinct rows/bank = free);
// V[k][4d] direct from global (64KB unique/block). kg-partials reduced via
// ss alias (8x1024), 8-way write conflict accepted (~1us).
__global__ __launch_bounds__(512, 4) void scores_ctx_kernel(const float* __restrict__ Qu,
    const float* __restrict__ Qv, const float* __restrict__ KT,
    const float* __restrict__ rel_table, const int* __restrict__ mask,
    const int* __restrict__ dist, const float* __restrict__ V,
    float* __restrict__ attn, float* __restrict__ ctx) {
    __shared__ float Qs[32][DHH];       // 4 KB
    __shared__ float Ps[32][NB];        // 1.5 KB
    __shared__ float psum[2][32];       // softmax half-sums
    __shared__ float ss[32 * 512];      // 64 KB; preamble aliases Qv8/rels; epilogue aliases partials
    const int blk = blockIdx.x;         // ((b*16 + qt32)*8 + h)
    const int h = blk & 7;
    const int rest = blk >> 3;
    const int qt32 = rest & 15;
    const int b = rest >> 4;
    const int q0 = qt32 * 32;
    const int t = threadIdx.x;
    const int w = t >> 6, l = t & 63;

    float* Qv8  = ss;                   // [32][32]  (dead after Ps compute)
    float* rels = ss + 1024;            // [12][33]  (dead after Ps compute)

    {
        const int r = t >> 4, c2 = (t & 15) * 2;
        const float2 qu2 = *(const float2*)&Qu[(b * LL + q0 + r) * DD + h * DHH + c2];
        const float2 qv2 = *(const float2*)&Qv[(b * LL + q0 + r) * DD + h * DHH + c2];
        Qs[r][c2]     = qu2.x;  Qs[r][c2 + 1]     = qu2.y;
        Qv8[r * DHH + c2] = qv2.x;  Qv8[r * DHH + c2 + 1] = qv2.y;
    }
    if (t < NB * DHH) {
        rels[(t >> 5) * 33 + (t & 31)] = rel_table[(t >> 5) * DD + h * DHH + (t & 31)];
    }
    __syncthreads();
    if (t < 32 * NB) {                  // Ps[r][bk] = dot32(Qv8[r], rels[bk])
        const int bk = t >> 5, r = t & 31;
        float a = 0.f;
#pragma unroll
        for (int d = 0; d < DHH; ++d) a = fmaf(Qv8[r * DHH + d], rels[bk * 33 + d], a);
        Ps[r][bk] = a;
    }
    __syncthreads();                    // Qv8/rels dead; ss writable

    // ---- Phase A: wave (rw,sw) does q rows 8rw..8rw+7 over k-half sw ----
    const int rw = w & 3, sw = w >> 2;
    const int r0 = 8 * rw;
    const int k0 = 4 * l + 256 * sw;
    const long kbase = (long)(b * HH + h) * DHH * LL;
    float sc[8][4];
#pragma unroll
    for (int r = 0; r < 8; ++r) {       // rel-P init via Ps gather
        const int4 dx = *(const int4*)&dist[(b * LL + q0 + r0 + r) * LL + k0];
        sc[r][0] = Ps[r0 + r][dx.x];  sc[r][1] = Ps[r0 + r][dx.y];
        sc[r][2] = Ps[r0 + r][dx.z];  sc[r][3] = Ps[r0 + r][dx.w];
    }
#pragma unroll 1
    for (int d8 = 0; d8 < DHH; d8 += 8) {
        float4 kv[8];                        // one K window serves 8 rows
#pragma unroll
        for (int j = 0; j < 8; ++j)
            kv[j] = *(const float4*)&KT[kbase + (long)(d8 + j) * LL + k0];
#pragma unroll
        for (int r = 0; r < 8; ++r) {
            const float4 qa4 = *(const float4*)&Qs[r0 + r][d8];      // wave-uniform
            const float4 qb4 = *(const float4*)&Qs[r0 + r][d8 + 4];
            const float* qa = (const float*)&qa4;
            const float* qb = (const float*)&qb4;
#pragma unroll
            for (int j = 0; j < 4; ++j) {
                sc[r][0] = fmaf(qa[j], kv[j].x, sc[r][0]);
                sc[r][1] = fmaf(qa[j], kv[j].y, sc[r][1]);
                sc[r][2] = fmaf(qa[j], kv[j].z, sc[r][2]);
                sc[r][3] = fmaf(qa[j], kv[j].w, sc[r][3]);
            }
#pragma unroll
            for (int j = 0; j < 4; ++j) {
                sc[r][0] = fmaf(qb[j], kv[j + 4].x, sc[r][0]);
                sc[r][1] = fmaf(qb[j], kv[j + 4].y, sc[r][1]);
                sc[r][2] = fmaf(qb[j], kv[j + 4].z, sc[r][2]);
                sc[r][3] = fmaf(qb[j], kv[j + 4].w, sc[r][3]);
            }
        }
    }
    float ev[8][4];
#pragma unroll
    for (int r = 0; r < 8; ++r) {
        const int4 mx = *(const int4*)&mask[(b * LL + q0 + r0 + r) * LL + k0];
        ev[r][0] = mx.x ? 0.f : __expf(sc[r][0]);
        ev[r][1] = mx.y ? 0.f : __expf(sc[r][1]);
        ev[r][2] = mx.z ? 0.f : __expf(sc[r][2]);
        ev[r][3] = mx.w ? 0.f : __expf(sc[r][3]);
        float sm = (ev[r][0] + ev[r][1]) + (ev[r][2] + ev[r][3]);
        for (int off = 32; off > 0; off >>= 1) sm += __shfl_xor(sm, off);
        if (l == 0) psum[sw][r0 + r] = sm;
    }
    __syncthreads();                    // halves combined
    {
        const int ch = k0 >> 7;
        const int oct = (k0 & 127) >> 3;
        const int h4 = k0 & 4;
#pragma unroll
        for (int r = 0; r < 8; ++r) {
            const int q = r0 + r;
            const float inv = 1.0f / (psum[0][q] + psum[1][q]);
            const float4 o = make_float4(ev[r][0] * inv, ev[r][1] * inv,
                                         ev[r][2] * inv, ev[r][3] * inv);
            *(float4*)&attn[((long)(b * HH + h) * LL + q0 + q) * LL + k0] = o;
            *(float4*)&ss[q * 512 + ch * 128 + (((oct ^ (q >> 2)) << 3) | h4)] = o;
        }
    }

    // ---- Phase B: ctx via 4q x 4d register tiles; V direct from global (L2) ----
    const int qt = t & 7;               // q-tile (rows 4qt..4qt+3); q>>2 == qt
    const int dt = (t >> 3) & 7;        // d-tile (cols 4dt..4dt+3)
    const int kg = t >> 6;              // == wave id; octets {kg, kg+8} per chunk
    const float* vbase = V + (long)b * LL * DD + h * DHH + dt * 4;
    float acc[4][4];
#pragma unroll
    for (int i = 0; i < 4; ++i)
#pragma unroll
        for (int jd = 0; jd < 4; ++jd) acc[i][jd] = 0.f;
    __syncthreads();                    // ss fully written
#pragma unroll 1
    for (int c = 0; c < 4; ++c) {
#pragma unroll
        for (int oo = 0; oo < 2; ++oo) {
            const int o = kg + 8 * oo;  // octet 0..15
#pragma unroll
            for (int ki = 0; ki < 2; ++ki) {
                float4 sv[4];           // 4 consecutive k of rows qt*4..qt*4+3
#pragma unroll
                for (int i = 0; i < 4; ++i)
                    sv[i] = *(const float4*)&ss[(qt * 4 + i) * 512 + c * 128 + (((o ^ qt) << 3) | (ki << 2))];
#pragma unroll
                for (int j = 0; j < 4; ++j) {
                    const int k = c * 128 + (o << 3) + (ki << 2) + j;
                    const float4 vf = *(const float4*)&vbase[k * DD];
                    const float w0 = ((const float*)&sv[0])[j];
                    const float w1 = ((const float*)&sv[1])[j];
                    const float w2 = ((const float*)&sv[2])[j];
                    const float w3 = ((const float*)&sv[3])[j];
                    acc[0][0] = fmaf(w0, vf.x, acc[0][0]); acc[0][1] = fmaf(w0, vf.y, acc[0][1]);
                    acc[0][2] = fmaf(w0, vf.z, acc[0][2]); acc[0][3] = fmaf(w0, vf.w, acc[0][3]);
                    acc[1][0] = fmaf(w1, vf.x, acc[1][0]); acc[1][1] = fmaf(w1, vf.y, acc[1][1]);
                    acc[1][2] = fmaf(w1, vf.z, acc[1][2]); acc[1][3] = fmaf(w1, vf.w, acc[1][3]);
                    acc[2][0] = fmaf(w2, vf.x, acc[2][0]); acc[2][1] = fmaf(w2, vf.y, acc[2][1]);
                    acc[2][2] = fmaf(w2, vf.z, acc[2][2]); acc[2][3] = fmaf(w2, vf.w, acc[2][3]);
                    acc[3][0] = fmaf(w3, vf.x, acc[3][0]); acc[3][1] = fmaf(w3, vf.y, acc[3][1]);
                    acc[3][2] = fmaf(w3, vf.z, acc[3][2]); acc[3][3] = fmaf(w3, vf.w, acc[3][3]);
                }
            }
        }
    }
    // kg-reduction: partials[kg][q][d] reuse ss (8 x 1024 floats of 16384).
    __syncthreads();                    // all phase-B ss reads done
#pragma unroll
    for (int i = 0; i < 4; ++i)
        *(float4*)&ss[kg * 1024 + (qt * 4 + i) * 32 + dt * 4] =
            make_float4(acc[i][0], acc[i][1], acc[i][2], acc[i][3]);
    __syncthreads();
    {
        const int qr = t >> 4;          // 0..31
        const int d2 = (t & 15) * 2;    // 0..30
        float v0 = 0.f, v1 = 0.f;
#pragma unroll
        for (int g = 0; g < 8; ++g) {
            const float2 p = *(const float2*)&ss[g * 1024 + qr * 32 + d2];
            v0 += p.x; v1 += p.y;
        }
        *(float2*)&ctx[(b * LL + q0 + qr) * DD + h * DHH + d2] = make_float2(v0, v1);
    }
}

// K3: output projection. Block = 4 rows (512 blocks = 2/CU); thread = 1 row x
// 4 cols; 8 W loads in flight. (r6 proven form.)
__global__ __launch_bounds__(256) void outproj_kernel(const float* __restrict__ ctx,
    const float* __restrict__ Wo, const float* __restrict__ bo,
    float* __restrict__ out) {
    __shared__ float xs[4][DD];
    const int r0 = blockIdx.x * 4;
    const int t = threadIdx.x;
    const int rg = t >> 6;
    const int c0 = (t & 63) * 4;
    ((float4*)&xs[0][0])[t] = ((const float4*)(ctx + r0 * DD))[t];
    __syncthreads();
    float4 acc = *(const float4*)&bo[c0];
    for (int i0 = 0; i0 < DD; i0 += 8) {
        float4 wv[8];
#pragma unroll
        for (int j = 0; j < 8; ++j) wv[j] = *(const float4*)&Wo[(i0 + j) * DD + c0];
        const float4 x0 = *(const float4*)&xs[rg][i0];
        const float4 x1 = *(const float4*)&xs[rg][i0 + 4];
        const float* xf0 = (const float*)&x0;
        const float* xf1 = (const float*)&x1;
#pragma unroll
        for (int j = 0; j < 4; ++j) {
            acc.x = fmaf(xf0[j], wv[j].x, acc.x);
            acc.y = fmaf(xf0[j], wv[j].y, acc.y);
            acc.z = fmaf(xf0[j], wv[j].z, acc.z);
            acc.w = fmaf(xf0[j], wv[j].w, acc.w);
        }
#pragma unroll
        for (int j = 0; j < 4; ++j) {
            acc.x = fmaf(xf1[j], wv[j + 4].x, acc.x);
            acc.y = fmaf(xf1[j], wv[j + 4].y, acc.y);
            acc.z = fmaf(xf1[j], wv[j + 4].z, acc.z);
            acc.w = fmaf(xf1[j], wv[j + 4].w, acc.w);
        }
    }
    *(float4*)&out[(r0 + rg) * DD + c0] = acc;
}

extern "C" void kernel_launch(void* const* d_in, const int* in_sizes, int n_in,
                              void* d_out, int out_size, void* d_ws, size_t ws_size,
                              hipStream_t stream) {
    const float* x    = (const float*)d_in[0];
    const int* mk     = (const int*)d_in[1];   // jax bool -> int32
    const int* dist   = (const int*)d_in[2];
    const float* Wq = (const float*)d_in[3];
    const float* bq = (const float*)d_in[4];
    const float* Wk = (const float*)d_in[5];
    const float* bk = (const float*)d_in[6];
    const float* Wv = (const float*)d_in[7];
    const float* bv = (const float*)d_in[8];
    const float* Wo = (const float*)d_in[9];
    const float* bo = (const float*)d_in[10];
    const float* rel_table = (const float*)d_in[11];
    const float* uvec = (const float*)d_in[12];
    const float* vvec = (const float*)d_in[13];

    float* out  = (float*)d_out;                 // (B,L,D)
    float* attn = out + BB * LL * DD;            // (B,H,L,L)

    float* Qu = (float*)d_ws;                    // q/sqrt(dh) + u
    float* Qv = Qu + BB * LL * DD;               // q/sqrt(dh) + v
    float* KT = Qv + BB * LL * DD;               // [B][H][DH][L]
    float* V  = KT + BB * LL * DD;               // [B][L][D]
    float* C  = V + BB * LL * DD;                // ctx (B,L,D); 10.5 MB ws total

    qkv_kernel<<<3 * 256, 256, 0, stream>>>(x, Wq, bq, Wk, bk, Wv, bv, uvec, vvec,
                                            Qu, Qv, KT, V);
    scores_ctx_kernel<<<BB * (LL / 32) * HH, 512, 0, stream>>>(Qu, Qv, KT, rel_table,
                                                               mk, dist, V, attn, C);
    outproj_kernel<<<BB * LL / 4, 256, 0, stream>>>(C, Wo, bo, out);
}